// Round 3
// baseline (4047.568 us; speedup 1.0000x reference)
//
#include <hip/hip_runtime.h>

#define NN 50000
#define NE 800000
#define SLOPE 0.2f
#define NEG_INF (-1e30f)
#define SCAN_B 196   // ceil(NN/256)

__device__ __forceinline__ float lrelu(float v) { return v >= 0.f ? v : SLOPE * v; }

// ---------------- register-tiled fp32 GEMM: H = X @ W  (NN x 128 * 128 x 128) ----------------
// 64 rows x 128 cols per block, 256 threads, each thread 8 rows x 4 cols.
__global__ __launch_bounds__(256) void gemm64(
    const float* __restrict__ X, const float* __restrict__ W, float* __restrict__ H)
{
    __shared__ float Xs[2][16][68];    // [buf][k][row], padded 64->68
    __shared__ float Wsh[2][16][128];  // [buf][k][col]
    const int t = threadIdx.x;
    const int rowBase = blockIdx.x * 64;

    // loader indices
    const int lr  = t >> 2;          // X row 0..63
    const int lk4 = (t & 3) * 4;     // X k offset 0,4,8,12
    const int wk  = t >> 5;          // W k row 0..7 (and +8)
    const int wc  = (t & 31) * 4;    // W col

    // compute indices
    const int rg = t >> 5;           // row group 0..7 -> rows rg*8..rg*8+7
    const int cg = t & 31;           // col group -> cols cg*4..cg*4+3
    const int r0 = rg * 8;
    const int c0 = cg * 4;

    const int xrow = min(rowBase + lr, NN - 1);

    // prologue: load chunk 0 into buf 0
    {
        float4 xv = *(const float4*)&X[(size_t)xrow * 128 + lk4];
        Xs[0][lk4 + 0][lr] = xv.x;
        Xs[0][lk4 + 1][lr] = xv.y;
        Xs[0][lk4 + 2][lr] = xv.z;
        Xs[0][lk4 + 3][lr] = xv.w;
        *(float4*)&Wsh[0][wk][wc]     = *(const float4*)&W[(size_t)wk * 128 + wc];
        *(float4*)&Wsh[0][wk + 8][wc] = *(const float4*)&W[(size_t)(wk + 8) * 128 + wc];
    }
    __syncthreads();

    float4 acc[8];
    #pragma unroll
    for (int j = 0; j < 8; ++j) acc[j] = make_float4(0.f, 0.f, 0.f, 0.f);

    #pragma unroll
    for (int kc = 0; kc < 8; ++kc) {
        const int buf = kc & 1;
        if (kc < 7) {
            const int nb = buf ^ 1;
            const int kb = (kc + 1) * 16;
            float4 xv = *(const float4*)&X[(size_t)xrow * 128 + kb + lk4];
            Xs[nb][lk4 + 0][lr] = xv.x;
            Xs[nb][lk4 + 1][lr] = xv.y;
            Xs[nb][lk4 + 2][lr] = xv.z;
            Xs[nb][lk4 + 3][lr] = xv.w;
            *(float4*)&Wsh[nb][wk][wc]     = *(const float4*)&W[(size_t)(kb + wk) * 128 + wc];
            *(float4*)&Wsh[nb][wk + 8][wc] = *(const float4*)&W[(size_t)(kb + wk + 8) * 128 + wc];
        }
        #pragma unroll
        for (int kk = 0; kk < 16; ++kk) {
            const float4 w  = *(const float4*)&Wsh[buf][kk][c0];
            const float4 xa = *(const float4*)&Xs[buf][kk][r0];
            const float4 xb = *(const float4*)&Xs[buf][kk][r0 + 4];
            acc[0].x = fmaf(xa.x, w.x, acc[0].x); acc[0].y = fmaf(xa.x, w.y, acc[0].y);
            acc[0].z = fmaf(xa.x, w.z, acc[0].z); acc[0].w = fmaf(xa.x, w.w, acc[0].w);
            acc[1].x = fmaf(xa.y, w.x, acc[1].x); acc[1].y = fmaf(xa.y, w.y, acc[1].y);
            acc[1].z = fmaf(xa.y, w.z, acc[1].z); acc[1].w = fmaf(xa.y, w.w, acc[1].w);
            acc[2].x = fmaf(xa.z, w.x, acc[2].x); acc[2].y = fmaf(xa.z, w.y, acc[2].y);
            acc[2].z = fmaf(xa.z, w.z, acc[2].z); acc[2].w = fmaf(xa.z, w.w, acc[2].w);
            acc[3].x = fmaf(xa.w, w.x, acc[3].x); acc[3].y = fmaf(xa.w, w.y, acc[3].y);
            acc[3].z = fmaf(xa.w, w.z, acc[3].z); acc[3].w = fmaf(xa.w, w.w, acc[3].w);
            acc[4].x = fmaf(xb.x, w.x, acc[4].x); acc[4].y = fmaf(xb.x, w.y, acc[4].y);
            acc[4].z = fmaf(xb.x, w.z, acc[4].z); acc[4].w = fmaf(xb.x, w.w, acc[4].w);
            acc[5].x = fmaf(xb.y, w.x, acc[5].x); acc[5].y = fmaf(xb.y, w.y, acc[5].y);
            acc[5].z = fmaf(xb.y, w.z, acc[5].z); acc[5].w = fmaf(xb.y, w.w, acc[5].w);
            acc[6].x = fmaf(xb.z, w.x, acc[6].x); acc[6].y = fmaf(xb.z, w.y, acc[6].y);
            acc[6].z = fmaf(xb.z, w.z, acc[6].z); acc[6].w = fmaf(xb.z, w.w, acc[6].w);
            acc[7].x = fmaf(xb.w, w.x, acc[7].x); acc[7].y = fmaf(xb.w, w.y, acc[7].y);
            acc[7].z = fmaf(xb.w, w.z, acc[7].z); acc[7].w = fmaf(xb.w, w.w, acc[7].w);
        }
        __syncthreads();
    }

    #pragma unroll
    for (int j = 0; j < 8; ++j) {
        const int r = rowBase + r0 + j;
        if (r < NN) *(float4*)&H[(size_t)r * 128 + c0] = acc[j];
    }
}

// ---------------- attention coefficients: asrc/adst[n,h] = <h[n,h,:], a_src/dst[h,:]> ----------------
__global__ __launch_bounds__(256) void attn_coef(
    const float* __restrict__ H, const float* __restrict__ a_src, const float* __restrict__ a_dst,
    float* __restrict__ asrc, float* __restrict__ adst)
{
    int i = blockIdx.x * 256 + threadIdx.x;   // i = n*8 + h
    if (i >= NN * 8) return;
    const int h = i & 7;
    const float4* hp = (const float4*)&H[(size_t)i * 16];
    const float4* ap = (const float4*)&a_src[h * 16];
    const float4* dp = (const float4*)&a_dst[h * 16];
    float s1 = 0.f, s2 = 0.f;
    #pragma unroll
    for (int j = 0; j < 4; ++j) {
        float4 hv = hp[j], av = ap[j], dv = dp[j];
        s1 += hv.x * av.x + hv.y * av.y + hv.z * av.z + hv.w * av.w;
        s2 += hv.x * dv.x + hv.y * dv.y + hv.z * dv.z + hv.w * dv.w;
    }
    asrc[i] = s1;
    adst[i] = s2;
}

// ---------------- CSR build ----------------
__global__ __launch_bounds__(256) void zero_counts(int* __restrict__ counts) {
    int i = blockIdx.x * 256 + threadIdx.x;
    if (i < NN) counts[i] = 0;
}

__global__ __launch_bounds__(256) void hist_dst(const int* __restrict__ dst,
                                                int* __restrict__ counts) {
    int e = blockIdx.x * 256 + threadIdx.x;
    if (e >= NE) return;
    int d = dst[e];
    if ((unsigned)d >= NN) d = 0;
    atomicAdd(&counts[d], 1);
}

__global__ __launch_bounds__(256) void block_sum(const int* __restrict__ counts,
                                                 int* __restrict__ bsum) {
    __shared__ int red[256];
    int t = threadIdx.x, i = blockIdx.x * 256 + t;
    red[t] = (i < NN) ? counts[i] : 0;
    __syncthreads();
    for (int s = 128; s > 0; s >>= 1) {
        if (t < s) red[t] += red[t + s];
        __syncthreads();
    }
    if (t == 0) bsum[blockIdx.x] = red[0];
}

__global__ __launch_bounds__(256) void scan_bsum(const int* __restrict__ bsum,
                                                 int* __restrict__ boff) {
    __shared__ int sh[256];
    int t = threadIdx.x;
    int v = (t < SCAN_B) ? bsum[t] : 0;
    sh[t] = v;
    __syncthreads();
    for (int d = 1; d < 256; d <<= 1) {
        int u = (t >= d) ? sh[t - d] : 0;
        __syncthreads();
        sh[t] += u;
        __syncthreads();
    }
    if (t < SCAN_B) boff[t] = sh[t] - v;   // exclusive
}

__global__ __launch_bounds__(256) void scan_final(
    const int* __restrict__ counts, const int* __restrict__ boff,
    int* __restrict__ off, int* __restrict__ cursor)
{
    __shared__ int sh[256];
    int t = threadIdx.x, i = blockIdx.x * 256 + t;
    int v = (i < NN) ? counts[i] : 0;
    sh[t] = v;
    __syncthreads();
    for (int d = 1; d < 256; d <<= 1) {
        int u = (t >= d) ? sh[t - d] : 0;
        __syncthreads();
        sh[t] += u;
        __syncthreads();
    }
    if (i < NN) {
        int o = boff[blockIdx.x] + sh[t] - v;
        off[i] = o;
        cursor[i] = o;
        if (i == NN - 1) off[NN] = o + v;
    }
}

__global__ __launch_bounds__(256) void scatter_csr(
    const int* __restrict__ src, const int* __restrict__ dst,
    int* __restrict__ cursor, int* __restrict__ csrE, int* __restrict__ csrS) {
    int e = blockIdx.x * 256 + threadIdx.x;
    if (e >= NE) return;
    int s = src[e], d = dst[e];
    if ((unsigned)s >= NN) s = 0;
    if ((unsigned)d >= NN) d = 0;
    int pos = atomicAdd(&cursor[d], 1);
    csrE[pos] = e;
    csrS[pos] = s;
}

// ---------------- fused per-node softmax + aggregate (one wave per node) ----------------
__global__ __launch_bounds__(256) void node_fused(
    const int* __restrict__ off, const int* __restrict__ csrE, const int* __restrict__ csrS,
    const float* __restrict__ asrc, const float* __restrict__ adst,
    const float* __restrict__ H, const float* __restrict__ bias,
    float* __restrict__ alpha, float* __restrict__ out)
{
    int wid = (blockIdx.x * 256 + threadIdx.x) >> 6;   // global wave id = node
    if (wid >= NN) return;
    const int lane = threadIdx.x & 63;
    const int n = wid;
    const int p0 = off[n], p1 = off[n + 1];
    const int deg = p1 - p0;
    const int h = lane & 7;      // head (softmax phase)
    const int el = lane >> 3;    // edge-local slot 0..7
    const float ad = adst[n * 8 + h];

    // phase 1: online (max, sum) per lane over strided edge chunks
    float m = NEG_INF, l = 0.f;
    for (int base = 0; base < deg; base += 8) {
        int i = base + el;
        if (i < deg) {
            int s = csrS[p0 + i];
            float v = lrelu(asrc[s * 8 + h] + ad);
            float nm = fmaxf(m, v);
            l = l * __expf(m - nm) + __expf(v - nm);
            m = nm;
        }
    }
    #pragma unroll
    for (int msk = 8; msk <= 32; msk <<= 1) {
        float m2 = __shfl_xor(m, msk);
        float l2 = __shfl_xor(l, msk);
        float nm = fmaxf(m, m2);
        l = l * __expf(m - nm) + l2 * __expf(m2 - nm);
        m = nm;
    }
    const float inv = 1.f / (l + 1e-16f);

    // phase 2: alpha write + gather-aggregate, chunks of 8 edges
    float2 acc = {0.f, 0.f};
    const int hc = lane >> 3;    // head of this lane's channel pair
    for (int base = 0; base < deg; base += 8) {
        int i = base + el;
        float a = 0.f;
        int s = 0;
        if (i < deg) {
            int p = p0 + i;
            int e = csrE[p];
            s = csrS[p];
            float v = lrelu(asrc[s * 8 + h] + ad);
            a = __expf(v - m) * inv;
            alpha[(size_t)e * 8 + h] = a;
        }
        int cnt = min(8, deg - base);
        for (int k = 0; k < cnt; ++k) {
            float ak = __shfl(a, k * 8 + hc);
            int sk = __shfl(s, k * 8);
            const float2 hv = *(const float2*)&H[(size_t)sk * 128 + lane * 2];
            acc.x = fmaf(hv.x, ak, acc.x);
            acc.y = fmaf(hv.y, ak, acc.y);
        }
    }
    float2 o;
    o.x = acc.x + bias[lane * 2];
    o.y = acc.y + bias[lane * 2 + 1];
    *(float2*)&out[(size_t)n * 128 + lane * 2] = o;
}

extern "C" void kernel_launch(void* const* d_in, const int* in_sizes, int n_in,
                              void* d_out, int out_size, void* d_ws, size_t ws_size,
                              hipStream_t stream)
{
    const float* x   = (const float*)d_in[0];
    const float* W1  = (const float*)d_in[1];
    const float* as1 = (const float*)d_in[2];
    const float* ad1 = (const float*)d_in[3];
    const float* b1  = (const float*)d_in[4];
    const float* W2  = (const float*)d_in[5];
    const float* as2 = (const float*)d_in[6];
    const float* ad2 = (const float*)d_in[7];
    const float* b2  = (const float*)d_in[8];
    const int*   ei  = (const int*)d_in[9];
    const int* srcp = ei;
    const int* dstp = ei + NE;

    float* outx   = (float*)d_out;            // [NN*128]
    float* alpha1 = outx + (size_t)NN * 128;  // [NE*8]
    float* alpha2 = alpha1 + (size_t)NE * 8;  // [NE*8]

    float* ws   = (float*)d_ws;
    float* hbuf = ws;                          // NN*128
    float* x1   = hbuf + (size_t)NN * 128;     // NN*128
    float* asrc = x1 + (size_t)NN * 128;       // NN*8
    float* adst = asrc + (size_t)NN * 8;       // NN*8
    int* counts = (int*)(adst + (size_t)NN * 8);   // NN
    int* off    = counts + NN;                      // NN+1
    int* cursor = off + NN + 1;                     // NN
    int* csrE   = cursor + NN;                      // NE
    int* csrS   = csrE + NE;                        // NE
    int* bsum   = csrS + NE;                        // SCAN_B
    int* boff   = bsum + SCAN_B;                    // SCAN_B

    int gemmGrid = (NN + 63) / 64;
    int coefGrid = (NN * 8 + 255) / 256;
    int nodeGrid = (NN + 3) / 4;           // 4 waves (nodes) per 256-thread block
    int edgeGrid = (NE + 255) / 256;
    int cntGrid  = (NN + 255) / 256;

    // ---- CSR build (shared by both layers) ----
    zero_counts<<<cntGrid, 256, 0, stream>>>(counts);
    hist_dst<<<edgeGrid, 256, 0, stream>>>(dstp, counts);
    block_sum<<<SCAN_B, 256, 0, stream>>>(counts, bsum);
    scan_bsum<<<1, 256, 0, stream>>>(bsum, boff);
    scan_final<<<SCAN_B, 256, 0, stream>>>(counts, boff, off, cursor);
    scatter_csr<<<edgeGrid, 256, 0, stream>>>(srcp, dstp, cursor, csrE, csrS);

    // ---- layer 1 ----
    gemm64<<<gemmGrid, 256, 0, stream>>>(x, W1, hbuf);
    attn_coef<<<coefGrid, 256, 0, stream>>>(hbuf, as1, ad1, asrc, adst);
    node_fused<<<nodeGrid, 256, 0, stream>>>(off, csrE, csrS, asrc, adst, hbuf, b1, alpha1, x1);

    // ---- layer 2 ----
    gemm64<<<gemmGrid, 256, 0, stream>>>(x1, W2, hbuf);
    attn_coef<<<coefGrid, 256, 0, stream>>>(hbuf, as2, ad2, asrc, adst);
    node_fused<<<nodeGrid, 256, 0, stream>>>(off, csrE, csrS, asrc, adst, hbuf, b2, alpha2, outx);
}

// Round 5
// 329.800 us; speedup vs baseline: 12.2728x; 12.2728x over previous
//
#include <hip/hip_runtime.h>

#define NN 50000
#define NE 800000
#define SLOPE 0.2f
#define NEG_INF (-1e30f)
#define SCAN_B 196   // ceil(NN/256)

__device__ __forceinline__ float lrelu(float v) { return v >= 0.f ? v : SLOPE * v; }

// ---------------- register-tiled fp32 GEMM: H = X @ W  (NN x 128 * 128 x 128) ----------------
// 64 rows x 128 cols per block, 256 threads, each thread 8 rows x 4 cols.
// Single LDS buffer + register prefetch; outer loop NOT unrolled (spill guard).
__global__ __launch_bounds__(256) void gemm64(
    const float* __restrict__ X, const float* __restrict__ W, float* __restrict__ H)
{
    __shared__ float Xs[16][68];    // [k][row], 64->68 pad
    __shared__ float Wsh[16][128];  // [k][col]
    const int t = threadIdx.x;
    const int rowBase = blockIdx.x * 64;

    const int lr  = t >> 2;          // X row 0..63
    const int lk4 = (t & 3) * 4;     // X k offset 0,4,8,12
    const int wk  = t >> 5;          // W k row 0..7 (and +8)
    const int wc  = (t & 31) * 4;    // W col

    const int r0 = (t >> 5) * 8;     // rows r0..r0+7
    const int c0 = (t & 31) * 4;     // cols c0..c0+3

    const int xrow = min(rowBase + lr, NN - 1);

    float4 xv  = *(const float4*)&X[(size_t)xrow * 128 + lk4];
    float4 wv0 = *(const float4*)&W[(size_t)wk * 128 + wc];
    float4 wv1 = *(const float4*)&W[(size_t)(wk + 8) * 128 + wc];

    float4 acc[8];
    #pragma unroll
    for (int j = 0; j < 8; ++j) acc[j] = make_float4(0.f, 0.f, 0.f, 0.f);

    #pragma unroll 1
    for (int kc = 0; kc < 8; ++kc) {
        __syncthreads();   // previous compute finished reading LDS
        Xs[lk4 + 0][lr] = xv.x;
        Xs[lk4 + 1][lr] = xv.y;
        Xs[lk4 + 2][lr] = xv.z;
        Xs[lk4 + 3][lr] = xv.w;
        *(float4*)&Wsh[wk][wc]     = wv0;
        *(float4*)&Wsh[wk + 8][wc] = wv1;
        __syncthreads();
        if (kc < 7) {
            const int kb = (kc + 1) * 16;
            xv  = *(const float4*)&X[(size_t)xrow * 128 + kb + lk4];
            wv0 = *(const float4*)&W[(size_t)(kb + wk) * 128 + wc];
            wv1 = *(const float4*)&W[(size_t)(kb + wk + 8) * 128 + wc];
        }
        #pragma unroll
        for (int kk = 0; kk < 16; ++kk) {
            const float4 w  = *(const float4*)&Wsh[kk][c0];
            const float4 xa = *(const float4*)&Xs[kk][r0];
            const float4 xb = *(const float4*)&Xs[kk][r0 + 4];
            acc[0].x = fmaf(xa.x, w.x, acc[0].x); acc[0].y = fmaf(xa.x, w.y, acc[0].y);
            acc[0].z = fmaf(xa.x, w.z, acc[0].z); acc[0].w = fmaf(xa.x, w.w, acc[0].w);
            acc[1].x = fmaf(xa.y, w.x, acc[1].x); acc[1].y = fmaf(xa.y, w.y, acc[1].y);
            acc[1].z = fmaf(xa.y, w.z, acc[1].z); acc[1].w = fmaf(xa.y, w.w, acc[1].w);
            acc[2].x = fmaf(xa.z, w.x, acc[2].x); acc[2].y = fmaf(xa.z, w.y, acc[2].y);
            acc[2].z = fmaf(xa.z, w.z, acc[2].z); acc[2].w = fmaf(xa.z, w.w, acc[2].w);
            acc[3].x = fmaf(xa.w, w.x, acc[3].x); acc[3].y = fmaf(xa.w, w.y, acc[3].y);
            acc[3].z = fmaf(xa.w, w.z, acc[3].z); acc[3].w = fmaf(xa.w, w.w, acc[3].w);
            acc[4].x = fmaf(xb.x, w.x, acc[4].x); acc[4].y = fmaf(xb.x, w.y, acc[4].y);
            acc[4].z = fmaf(xb.x, w.z, acc[4].z); acc[4].w = fmaf(xb.x, w.w, acc[4].w);
            acc[5].x = fmaf(xb.y, w.x, acc[5].x); acc[5].y = fmaf(xb.y, w.y, acc[5].y);
            acc[5].z = fmaf(xb.y, w.z, acc[5].z); acc[5].w = fmaf(xb.y, w.w, acc[5].w);
            acc[6].x = fmaf(xb.z, w.x, acc[6].x); acc[6].y = fmaf(xb.z, w.y, acc[6].y);
            acc[6].z = fmaf(xb.z, w.z, acc[6].z); acc[6].w = fmaf(xb.z, w.w, acc[6].w);
            acc[7].x = fmaf(xb.w, w.x, acc[7].x); acc[7].y = fmaf(xb.w, w.y, acc[7].y);
            acc[7].z = fmaf(xb.w, w.z, acc[7].z); acc[7].w = fmaf(xb.w, w.w, acc[7].w);
        }
    }

    #pragma unroll
    for (int j = 0; j < 8; ++j) {
        const int r = rowBase + r0 + j;
        if (r < NN) *(float4*)&H[(size_t)r * 128 + c0] = acc[j];
    }
}

// ---------------- attention coefficients ----------------
__global__ __launch_bounds__(256) void attn_coef(
    const float* __restrict__ H, const float* __restrict__ a_src, const float* __restrict__ a_dst,
    float* __restrict__ asrc, float* __restrict__ adst)
{
    int i = blockIdx.x * 256 + threadIdx.x;   // i = n*8 + h
    if (i >= NN * 8) return;
    const int h = i & 7;
    const float4* hp = (const float4*)&H[(size_t)i * 16];
    const float4* ap = (const float4*)&a_src[h * 16];
    const float4* dp = (const float4*)&a_dst[h * 16];
    float s1 = 0.f, s2 = 0.f;
    #pragma unroll
    for (int j = 0; j < 4; ++j) {
        float4 hv = hp[j], av = ap[j], dv = dp[j];
        s1 += hv.x * av.x + hv.y * av.y + hv.z * av.z + hv.w * av.w;
        s2 += hv.x * dv.x + hv.y * dv.y + hv.z * dv.z + hv.w * dv.w;
    }
    asrc[i] = s1;
    adst[i] = s2;
}

// ---------------- CSR build ----------------
__global__ __launch_bounds__(256) void zero_counts(int* __restrict__ counts) {
    int i = blockIdx.x * 256 + threadIdx.x;
    if (i < NN) counts[i] = 0;
}

__global__ __launch_bounds__(256) void hist_dst(const int* __restrict__ dst,
                                                int* __restrict__ counts) {
    int e = blockIdx.x * 256 + threadIdx.x;
    if (e >= NE) return;
    int d = dst[e];
    if ((unsigned)d >= NN) d = 0;
    atomicAdd(&counts[d], 1);
}

__global__ __launch_bounds__(256) void block_sum(const int* __restrict__ counts,
                                                 int* __restrict__ bsum) {
    __shared__ int red[256];
    int t = threadIdx.x, i = blockIdx.x * 256 + t;
    red[t] = (i < NN) ? counts[i] : 0;
    __syncthreads();
    for (int s = 128; s > 0; s >>= 1) {
        if (t < s) red[t] += red[t + s];
        __syncthreads();
    }
    if (t == 0) bsum[blockIdx.x] = red[0];
}

__global__ __launch_bounds__(256) void scan_bsum(const int* __restrict__ bsum,
                                                 int* __restrict__ boff) {
    __shared__ int sh[256];
    int t = threadIdx.x;
    int v = (t < SCAN_B) ? bsum[t] : 0;
    sh[t] = v;
    __syncthreads();
    for (int d = 1; d < 256; d <<= 1) {
        int u = (t >= d) ? sh[t - d] : 0;
        __syncthreads();
        sh[t] += u;
        __syncthreads();
    }
    if (t < SCAN_B) boff[t] = sh[t] - v;   // exclusive
}

__global__ __launch_bounds__(256) void scan_final(
    const int* __restrict__ counts, const int* __restrict__ boff,
    int* __restrict__ off, int* __restrict__ cursor)
{
    __shared__ int sh[256];
    int t = threadIdx.x, i = blockIdx.x * 256 + t;
    int v = (i < NN) ? counts[i] : 0;
    sh[t] = v;
    __syncthreads();
    for (int d = 1; d < 256; d <<= 1) {
        int u = (t >= d) ? sh[t - d] : 0;
        __syncthreads();
        sh[t] += u;
        __syncthreads();
    }
    if (i < NN) {
        int o = boff[blockIdx.x] + sh[t] - v;
        off[i] = o;
        cursor[i] = o;
        if (i == NN - 1) off[NN] = o + v;
    }
}

__global__ __launch_bounds__(256) void scatter_csr(
    const int* __restrict__ src, const int* __restrict__ dst,
    int* __restrict__ cursor, int* __restrict__ csrE, int* __restrict__ csrS) {
    int e = blockIdx.x * 256 + threadIdx.x;
    if (e >= NE) return;
    int s = src[e], d = dst[e];
    if ((unsigned)s >= NN) s = 0;
    if ((unsigned)d >= NN) d = 0;
    int pos = atomicAdd(&cursor[d], 1);
    csrE[pos] = e;
    csrS[pos] = s;
}

// ---------------- fused per-node softmax + aggregate (one wave per node) ----------------
__global__ __launch_bounds__(256) void node_fused(
    const int* __restrict__ off, const int* __restrict__ csrE, const int* __restrict__ csrS,
    const float* __restrict__ asrc, const float* __restrict__ adst,
    const float* __restrict__ H, const float* __restrict__ bias,
    float* __restrict__ alpha, float* __restrict__ out)
{
    int wid = (blockIdx.x * 256 + threadIdx.x) >> 6;   // global wave id = node
    if (wid >= NN) return;
    const int lane = threadIdx.x & 63;
    const int n = wid;
    const int p0 = off[n], p1 = off[n + 1];
    const int deg = p1 - p0;
    const int h = lane & 7;      // head (softmax lanes)
    const int el = lane >> 3;    // edge-local slot 0..7
    const float ad = adst[n * 8 + h];

    // phase 1: online (max, sum)
    float m = NEG_INF, l = 0.f;
    for (int base = 0; base < deg; base += 8) {
        int i = base + el;
        if (i < deg) {
            int s = csrS[p0 + i];
            float v = lrelu(asrc[s * 8 + h] + ad);
            float nm = fmaxf(m, v);
            l = l * __expf(m - nm) + __expf(v - nm);
            m = nm;
        }
    }
    #pragma unroll
    for (int msk = 8; msk <= 32; msk <<= 1) {
        float m2 = __shfl_xor(m, msk);
        float l2 = __shfl_xor(l, msk);
        float nm = fmaxf(m, m2);
        l = l * __expf(m - nm) + l2 * __expf(m2 - nm);
        m = nm;
    }
    const float inv = 1.f / (l + 1e-16f);

    // phase 2: alpha write + float4 gather-aggregate.
    // Wave halves split edges (half 0 even k, half 1 odd k) BUT the loop is
    // convergent: uniform trip count, shfl index clamped to a valid lane,
    // contribution predicated branchlessly. (Divergent-trip-count loops
    // containing __shfl are UB — round-4 bug.)
    const int half = lane >> 5;
    const int cl = lane & 31;
    const int hh = cl >> 2;
    float4 acc4 = make_float4(0.f, 0.f, 0.f, 0.f);
    for (int base = 0; base < deg; base += 8) {
        int i = base + el;
        float a = 0.f;
        int s = 0;
        if (i < deg) {
            int p = p0 + i;
            int e = csrE[p];
            s = csrS[p];
            float v = lrelu(asrc[s * 8 + h] + ad);
            a = __expf(v - m) * inv;
            alpha[(size_t)e * 8 + h] = a;
        }
        const int cnt = min(8, deg - base);
        for (int kb2 = 0; kb2 < cnt; kb2 += 2) {       // uniform trip count
            const int kw = kb2 + half;                 // this half's edge slot
            const int kc2 = min(kw, cnt - 1);          // clamped valid slot
            float ak = __shfl(a, kc2 * 8 + hh);
            int   sk = __shfl(s, kc2 * 8);
            const float am = (kw < cnt) ? ak : 0.f;    // branchless predication
            const float4 hv = *(const float4*)&H[(size_t)sk * 128 + cl * 4];
            acc4.x = fmaf(hv.x, am, acc4.x);
            acc4.y = fmaf(hv.y, am, acc4.y);
            acc4.z = fmaf(hv.z, am, acc4.z);
            acc4.w = fmaf(hv.w, am, acc4.w);
        }
    }
    // combine halves
    acc4.x += __shfl_xor(acc4.x, 32);
    acc4.y += __shfl_xor(acc4.y, 32);
    acc4.z += __shfl_xor(acc4.z, 32);
    acc4.w += __shfl_xor(acc4.w, 32);
    if (half == 0) {
        const float4 bv = *(const float4*)&bias[cl * 4];
        float4 o;
        o.x = acc4.x + bv.x;
        o.y = acc4.y + bv.y;
        o.z = acc4.z + bv.z;
        o.w = acc4.w + bv.w;
        *(float4*)&out[(size_t)n * 128 + cl * 4] = o;
    }
}

extern "C" void kernel_launch(void* const* d_in, const int* in_sizes, int n_in,
                              void* d_out, int out_size, void* d_ws, size_t ws_size,
                              hipStream_t stream)
{
    const float* x   = (const float*)d_in[0];
    const float* W1  = (const float*)d_in[1];
    const float* as1 = (const float*)d_in[2];
    const float* ad1 = (const float*)d_in[3];
    const float* b1  = (const float*)d_in[4];
    const float* W2  = (const float*)d_in[5];
    const float* as2 = (const float*)d_in[6];
    const float* ad2 = (const float*)d_in[7];
    const float* b2  = (const float*)d_in[8];
    const int*   ei  = (const int*)d_in[9];
    const int* srcp = ei;
    const int* dstp = ei + NE;

    float* outx   = (float*)d_out;            // [NN*128]
    float* alpha1 = outx + (size_t)NN * 128;  // [NE*8]
    float* alpha2 = alpha1 + (size_t)NE * 8;  // [NE*8]

    float* ws   = (float*)d_ws;
    float* hbuf = ws;                          // NN*128
    float* x1   = hbuf + (size_t)NN * 128;     // NN*128
    float* asrc = x1 + (size_t)NN * 128;       // NN*8
    float* adst = asrc + (size_t)NN * 8;       // NN*8
    int* counts = (int*)(adst + (size_t)NN * 8);   // NN
    int* off    = counts + NN;                      // NN+1
    int* cursor = off + NN + 1;                     // NN
    int* csrE   = cursor + NN;                      // NE
    int* csrS   = csrE + NE;                        // NE
    int* bsum   = csrS + NE;                        // SCAN_B
    int* boff   = bsum + SCAN_B;                    // SCAN_B

    int gemmGrid = (NN + 63) / 64;
    int coefGrid = (NN * 8 + 255) / 256;
    int nodeGrid = (NN + 3) / 4;           // 4 waves (nodes) per 256-thread block
    int edgeGrid = (NE + 255) / 256;
    int cntGrid  = (NN + 255) / 256;

    // ---- CSR build (shared by both layers) ----
    zero_counts<<<cntGrid, 256, 0, stream>>>(counts);
    hist_dst<<<edgeGrid, 256, 0, stream>>>(dstp, counts);
    block_sum<<<SCAN_B, 256, 0, stream>>>(counts, bsum);
    scan_bsum<<<1, 256, 0, stream>>>(bsum, boff);
    scan_final<<<SCAN_B, 256, 0, stream>>>(counts, boff, off, cursor);
    scatter_csr<<<edgeGrid, 256, 0, stream>>>(srcp, dstp, cursor, csrE, csrS);

    // ---- layer 1 ----
    gemm64<<<gemmGrid, 256, 0, stream>>>(x, W1, hbuf);
    attn_coef<<<coefGrid, 256, 0, stream>>>(hbuf, as1, ad1, asrc, adst);
    node_fused<<<nodeGrid, 256, 0, stream>>>(off, csrE, csrS, asrc, adst, hbuf, b1, alpha1, x1);

    // ---- layer 2 ----
    gemm64<<<gemmGrid, 256, 0, stream>>>(x1, W2, hbuf);
    attn_coef<<<coefGrid, 256, 0, stream>>>(hbuf, as2, ad2, asrc, adst);
    node_fused<<<nodeGrid, 256, 0, stream>>>(off, csrE, csrS, asrc, adst, hbuf, b2, alpha2, outx);
}

// Round 6
// 313.237 us; speedup vs baseline: 12.9217x; 1.0529x over previous
//
#include <hip/hip_runtime.h>

#define NN 50000
#define NE 800000
#define SLOPE 0.2f
#define NEG_INF (-1e30f)
#define SCAN_B 196   // ceil(NN/256)
#define ECAP 64      // cached edges per wave in node_fused

__device__ __forceinline__ float lrelu(float v) { return v >= 0.f ? v : SLOPE * v; }

// ---------------- fp32 GEMM + fused attention coefficients ----------------
// H = X @ W (NN x 128 * 128 x 128); asrc/adst[n,h] = <h[n,h,:], a_src/dst[h,:]>
// 64 rows x 128 cols per block, 256 threads, 8 rows x 4 cols each.
// Double-buffered LDS (one barrier per k-chunk); outer loop NOT unrolled.
__global__ __launch_bounds__(256) void gemm_attn64(
    const float* __restrict__ X, const float* __restrict__ W,
    const float* __restrict__ a_src, const float* __restrict__ a_dst,
    float* __restrict__ H, float* __restrict__ asrc, float* __restrict__ adst)
{
    __shared__ float Xs[2][16][68];    // [buf][k][row], 64->68 pad
    __shared__ float Wsh[2][16][128];  // [buf][k][col]
    const int t = threadIdx.x;
    const int rowBase = blockIdx.x * 64;

    const int lr  = t >> 2;          // X row 0..63
    const int lk4 = (t & 3) * 4;     // X k offset 0,4,8,12
    const int wk  = t >> 5;          // W k row 0..7 (and +8)
    const int wc  = (t & 31) * 4;    // W col

    const int r0 = (t >> 5) * 8;     // rows r0..r0+7
    const int c0 = (t & 31) * 4;     // cols c0..c0+3

    const int xrow = min(rowBase + lr, NN - 1);

    // chunk 0 -> LDS buf 0
    float4 xv  = *(const float4*)&X[(size_t)xrow * 128 + lk4];
    float4 wv0 = *(const float4*)&W[(size_t)wk * 128 + wc];
    float4 wv1 = *(const float4*)&W[(size_t)(wk + 8) * 128 + wc];
    Xs[0][lk4 + 0][lr] = xv.x;
    Xs[0][lk4 + 1][lr] = xv.y;
    Xs[0][lk4 + 2][lr] = xv.z;
    Xs[0][lk4 + 3][lr] = xv.w;
    *(float4*)&Wsh[0][wk][wc]     = wv0;
    *(float4*)&Wsh[0][wk + 8][wc] = wv1;
    // prefetch chunk 1 into registers
    xv  = *(const float4*)&X[(size_t)xrow * 128 + 16 + lk4];
    wv0 = *(const float4*)&W[(size_t)(16 + wk) * 128 + wc];
    wv1 = *(const float4*)&W[(size_t)(16 + wk + 8) * 128 + wc];
    __syncthreads();

    float4 acc[8];
    #pragma unroll
    for (int j = 0; j < 8; ++j) acc[j] = make_float4(0.f, 0.f, 0.f, 0.f);

    #pragma unroll 1
    for (int kc = 0; kc < 8; ++kc) {
        const int cur = kc & 1;
        if (kc < 7) {   // write prefetched chunk kc+1 into the other buffer
            const int nxt = cur ^ 1;
            Xs[nxt][lk4 + 0][lr] = xv.x;
            Xs[nxt][lk4 + 1][lr] = xv.y;
            Xs[nxt][lk4 + 2][lr] = xv.z;
            Xs[nxt][lk4 + 3][lr] = xv.w;
            *(float4*)&Wsh[nxt][wk][wc]     = wv0;
            *(float4*)&Wsh[nxt][wk + 8][wc] = wv1;
        }
        if (kc < 6) {   // prefetch chunk kc+2 into registers
            const int kb = (kc + 2) * 16;
            xv  = *(const float4*)&X[(size_t)xrow * 128 + kb + lk4];
            wv0 = *(const float4*)&W[(size_t)(kb + wk) * 128 + wc];
            wv1 = *(const float4*)&W[(size_t)(kb + wk + 8) * 128 + wc];
        }
        #pragma unroll
        for (int kk = 0; kk < 16; ++kk) {
            const float4 w  = *(const float4*)&Wsh[cur][kk][c0];
            const float4 xa = *(const float4*)&Xs[cur][kk][r0];
            const float4 xb = *(const float4*)&Xs[cur][kk][r0 + 4];
            acc[0].x = fmaf(xa.x, w.x, acc[0].x); acc[0].y = fmaf(xa.x, w.y, acc[0].y);
            acc[0].z = fmaf(xa.x, w.z, acc[0].z); acc[0].w = fmaf(xa.x, w.w, acc[0].w);
            acc[1].x = fmaf(xa.y, w.x, acc[1].x); acc[1].y = fmaf(xa.y, w.y, acc[1].y);
            acc[1].z = fmaf(xa.y, w.z, acc[1].z); acc[1].w = fmaf(xa.y, w.w, acc[1].w);
            acc[2].x = fmaf(xa.z, w.x, acc[2].x); acc[2].y = fmaf(xa.z, w.y, acc[2].y);
            acc[2].z = fmaf(xa.z, w.z, acc[2].z); acc[2].w = fmaf(xa.z, w.w, acc[2].w);
            acc[3].x = fmaf(xa.w, w.x, acc[3].x); acc[3].y = fmaf(xa.w, w.y, acc[3].y);
            acc[3].z = fmaf(xa.w, w.z, acc[3].z); acc[3].w = fmaf(xa.w, w.w, acc[3].w);
            acc[4].x = fmaf(xb.x, w.x, acc[4].x); acc[4].y = fmaf(xb.x, w.y, acc[4].y);
            acc[4].z = fmaf(xb.x, w.z, acc[4].z); acc[4].w = fmaf(xb.x, w.w, acc[4].w);
            acc[5].x = fmaf(xb.y, w.x, acc[5].x); acc[5].y = fmaf(xb.y, w.y, acc[5].y);
            acc[5].z = fmaf(xb.y, w.z, acc[5].z); acc[5].w = fmaf(xb.y, w.w, acc[5].w);
            acc[6].x = fmaf(xb.z, w.x, acc[6].x); acc[6].y = fmaf(xb.z, w.y, acc[6].y);
            acc[6].z = fmaf(xb.z, w.z, acc[6].z); acc[6].w = fmaf(xb.z, w.w, acc[6].w);
            acc[7].x = fmaf(xb.w, w.x, acc[7].x); acc[7].y = fmaf(xb.w, w.y, acc[7].y);
            acc[7].z = fmaf(xb.w, w.z, acc[7].z); acc[7].w = fmaf(xb.w, w.w, acc[7].w);
        }
        __syncthreads();
    }

    // epilogue: H store + fused per-head attention dots.
    // a vectors are [H=8][C=16] flat 128 => coeff for flat col c is a[c].
    const float4 asv = *(const float4*)&a_src[c0];
    const float4 adv = *(const float4*)&a_dst[c0];
    const int cl = t & 31;
    const int hh = cl >> 2;          // head of this col group
    #pragma unroll
    for (int j = 0; j < 8; ++j) {
        const int r = rowBase + r0 + j;
        if (r < NN) *(float4*)&H[(size_t)r * 128 + c0] = acc[j];
        float s1 = acc[j].x * asv.x + acc[j].y * asv.y + acc[j].z * asv.z + acc[j].w * asv.w;
        float s2 = acc[j].x * adv.x + acc[j].y * adv.y + acc[j].z * adv.z + acc[j].w * adv.w;
        s1 += __shfl_xor(s1, 1); s1 += __shfl_xor(s1, 2);
        s2 += __shfl_xor(s2, 1); s2 += __shfl_xor(s2, 2);
        if ((cl & 3) == 0 && r < NN) {
            asrc[r * 8 + hh] = s1;
            adst[r * 8 + hh] = s2;
        }
    }
}

// ---------------- CSR build ----------------
__global__ __launch_bounds__(256) void zero_counts(int* __restrict__ counts) {
    int i = blockIdx.x * 256 + threadIdx.x;
    if (i < NN) counts[i] = 0;
}

__global__ __launch_bounds__(256) void hist_dst(const int* __restrict__ dst,
                                                int* __restrict__ counts) {
    int e = blockIdx.x * 256 + threadIdx.x;
    if (e >= NE) return;
    int d = dst[e];
    if ((unsigned)d >= NN) d = 0;
    atomicAdd(&counts[d], 1);
}

__global__ __launch_bounds__(256) void block_sum(const int* __restrict__ counts,
                                                 int* __restrict__ bsum) {
    __shared__ int red[256];
    int t = threadIdx.x, i = blockIdx.x * 256 + t;
    red[t] = (i < NN) ? counts[i] : 0;
    __syncthreads();
    for (int s = 128; s > 0; s >>= 1) {
        if (t < s) red[t] += red[t + s];
        __syncthreads();
    }
    if (t == 0) bsum[blockIdx.x] = red[0];
}

__global__ __launch_bounds__(256) void scan_bsum(const int* __restrict__ bsum,
                                                 int* __restrict__ boff) {
    __shared__ int sh[256];
    int t = threadIdx.x;
    int v = (t < SCAN_B) ? bsum[t] : 0;
    sh[t] = v;
    __syncthreads();
    for (int d = 1; d < 256; d <<= 1) {
        int u = (t >= d) ? sh[t - d] : 0;
        __syncthreads();
        sh[t] += u;
        __syncthreads();
    }
    if (t < SCAN_B) boff[t] = sh[t] - v;   // exclusive
}

__global__ __launch_bounds__(256) void scan_final(
    const int* __restrict__ counts, const int* __restrict__ boff,
    int* __restrict__ off, int* __restrict__ cursor)
{
    __shared__ int sh[256];
    int t = threadIdx.x, i = blockIdx.x * 256 + t;
    int v = (i < NN) ? counts[i] : 0;
    sh[t] = v;
    __syncthreads();
    for (int d = 1; d < 256; d <<= 1) {
        int u = (t >= d) ? sh[t - d] : 0;
        __syncthreads();
        sh[t] += u;
        __syncthreads();
    }
    if (i < NN) {
        int o = boff[blockIdx.x] + sh[t] - v;
        off[i] = o;
        cursor[i] = o;
        if (i == NN - 1) off[NN] = o + v;
    }
}

__global__ __launch_bounds__(256) void scatter_csr(
    const int* __restrict__ src, const int* __restrict__ dst,
    int* __restrict__ cursor, int* __restrict__ csrE, int* __restrict__ csrS) {
    int e = blockIdx.x * 256 + threadIdx.x;
    if (e >= NE) return;
    int s = src[e], d = dst[e];
    if ((unsigned)s >= NN) s = 0;
    if ((unsigned)d >= NN) d = 0;
    int pos = atomicAdd(&cursor[d], 1);
    csrE[pos] = e;
    csrS[pos] = s;
}

// ---------------- fused per-node softmax + aggregate (one wave per node) ----------------
__global__ __launch_bounds__(256) void node_fused(
    const int* __restrict__ off, const int* __restrict__ csrE, const int* __restrict__ csrS,
    const float* __restrict__ asrc, const float* __restrict__ adst,
    const float* __restrict__ H, const float* __restrict__ bias,
    float* __restrict__ alpha, float* __restrict__ out)
{
    __shared__ float ecache[4][ECAP * 8];   // per-wave e-values [i][h]
    __shared__ int   scache[4][ECAP];       // per-wave src ids
    const int w = threadIdx.x >> 6;         // wave within block
    int wid = (blockIdx.x * 256 + threadIdx.x) >> 6;
    if (wid >= NN) return;
    const int lane = threadIdx.x & 63;
    const int n = wid;
    const int p0 = off[n], p1 = off[n + 1];
    const int deg = p1 - p0;
    const int h = lane & 7;      // head (softmax lanes)
    const int el = lane >> 3;    // edge-local slot 0..7
    const float ad = adst[n * 8 + h];

    // phase 1: online (max, sum), caching e-values + src ids in LDS
    float m = NEG_INF, l = 0.f;
    for (int base = 0; base < deg; base += 8) {
        int i = base + el;
        if (i < deg) {
            int s = csrS[p0 + i];
            float v = lrelu(asrc[s * 8 + h] + ad);
            if (i < ECAP) {
                ecache[w][i * 8 + h] = v;
                if (h == 0) scache[w][i] = s;
            }
            float nm = fmaxf(m, v);
            l = l * __expf(m - nm) + __expf(v - nm);
            m = nm;
        }
    }
    #pragma unroll
    for (int msk = 8; msk <= 32; msk <<= 1) {
        float m2 = __shfl_xor(m, msk);
        float l2 = __shfl_xor(l, msk);
        float nm = fmaxf(m, m2);
        l = l * __expf(m - nm) + l2 * __expf(m2 - nm);
        m = nm;
    }
    const float inv = 1.f / (l + 1e-16f);

    // phase 2: alpha write + float4 gather-aggregate.
    // Convergent loops only: uniform trip count, clamped shfl index,
    // branchless predication (divergent __shfl is UB — round-4 lesson).
    const int half = lane >> 5;
    const int cl = lane & 31;
    const int hh = cl >> 2;
    float4 acc4 = make_float4(0.f, 0.f, 0.f, 0.f);
    for (int base = 0; base < deg; base += 8) {
        int i = base + el;
        float a = 0.f;
        int s = 0;
        if (i < deg) {
            int p = p0 + i;
            int e = csrE[p];
            float v;
            if (i < ECAP) {
                s = scache[w][i];
                v = ecache[w][i * 8 + h];
            } else {
                s = csrS[p];
                v = lrelu(asrc[s * 8 + h] + ad);
            }
            a = __expf(v - m) * inv;
            alpha[(size_t)e * 8 + h] = a;
        }
        const int cnt = min(8, deg - base);
        for (int kb2 = 0; kb2 < cnt; kb2 += 2) {       // uniform trip count
            const int kw = kb2 + half;                 // this half's edge slot
            const int kc2 = min(kw, cnt - 1);          // clamped valid slot
            float ak = __shfl(a, kc2 * 8 + hh);
            int   sk = __shfl(s, kc2 * 8);
            const float am = (kw < cnt) ? ak : 0.f;    // branchless predication
            const float4 hv = *(const float4*)&H[(size_t)sk * 128 + cl * 4];
            acc4.x = fmaf(hv.x, am, acc4.x);
            acc4.y = fmaf(hv.y, am, acc4.y);
            acc4.z = fmaf(hv.z, am, acc4.z);
            acc4.w = fmaf(hv.w, am, acc4.w);
        }
    }
    // combine halves
    acc4.x += __shfl_xor(acc4.x, 32);
    acc4.y += __shfl_xor(acc4.y, 32);
    acc4.z += __shfl_xor(acc4.z, 32);
    acc4.w += __shfl_xor(acc4.w, 32);
    if (half == 0) {
        const float4 bv = *(const float4*)&bias[cl * 4];
        float4 o;
        o.x = acc4.x + bv.x;
        o.y = acc4.y + bv.y;
        o.z = acc4.z + bv.z;
        o.w = acc4.w + bv.w;
        *(float4*)&out[(size_t)n * 128 + cl * 4] = o;
    }
}

extern "C" void kernel_launch(void* const* d_in, const int* in_sizes, int n_in,
                              void* d_out, int out_size, void* d_ws, size_t ws_size,
                              hipStream_t stream)
{
    const float* x   = (const float*)d_in[0];
    const float* W1  = (const float*)d_in[1];
    const float* as1 = (const float*)d_in[2];
    const float* ad1 = (const float*)d_in[3];
    const float* b1  = (const float*)d_in[4];
    const float* W2  = (const float*)d_in[5];
    const float* as2 = (const float*)d_in[6];
    const float* ad2 = (const float*)d_in[7];
    const float* b2  = (const float*)d_in[8];
    const int*   ei  = (const int*)d_in[9];
    const int* srcp = ei;
    const int* dstp = ei + NE;

    float* outx   = (float*)d_out;            // [NN*128]
    float* alpha1 = outx + (size_t)NN * 128;  // [NE*8]
    float* alpha2 = alpha1 + (size_t)NE * 8;  // [NE*8]

    float* ws   = (float*)d_ws;
    float* hbuf = ws;                          // NN*128
    float* x1   = hbuf + (size_t)NN * 128;     // NN*128
    float* asrc = x1 + (size_t)NN * 128;       // NN*8
    float* adst = asrc + (size_t)NN * 8;       // NN*8
    int* counts = (int*)(adst + (size_t)NN * 8);   // NN
    int* off    = counts + NN;                      // NN+1
    int* cursor = off + NN + 1;                     // NN
    int* csrE   = cursor + NN;                      // NE
    int* csrS   = csrE + NE;                        // NE
    int* bsum   = csrS + NE;                        // SCAN_B
    int* boff   = bsum + SCAN_B;                    // SCAN_B

    int gemmGrid = (NN + 63) / 64;
    int nodeGrid = (NN + 3) / 4;           // 4 waves (nodes) per 256-thread block
    int edgeGrid = (NE + 255) / 256;
    int cntGrid  = (NN + 255) / 256;

    // ---- CSR build (shared by both layers) ----
    zero_counts<<<cntGrid, 256, 0, stream>>>(counts);
    hist_dst<<<edgeGrid, 256, 0, stream>>>(dstp, counts);
    block_sum<<<SCAN_B, 256, 0, stream>>>(counts, bsum);
    scan_bsum<<<1, 256, 0, stream>>>(bsum, boff);
    scan_final<<<SCAN_B, 256, 0, stream>>>(counts, boff, off, cursor);
    scatter_csr<<<edgeGrid, 256, 0, stream>>>(srcp, dstp, cursor, csrE, csrS);

    // ---- layer 1 ----
    gemm_attn64<<<gemmGrid, 256, 0, stream>>>(x, W1, as1, ad1, hbuf, asrc, adst);
    node_fused<<<nodeGrid, 256, 0, stream>>>(off, csrE, csrS, asrc, adst, hbuf, b1, alpha1, x1);

    // ---- layer 2 ----
    gemm_attn64<<<gemmGrid, 256, 0, stream>>>(x1, W2, as2, ad2, hbuf, asrc, adst);
    node_fused<<<nodeGrid, 256, 0, stream>>>(off, csrE, csrS, asrc, adst, hbuf, b2, alpha2, outx);
}

// Round 7
// 274.662 us; speedup vs baseline: 14.7365x; 1.1404x over previous
//
#include <hip/hip_runtime.h>
#include <hip/hip_fp16.h>

#define NN 50000
#define NE 800000
#define SLOPE 0.2f
#define NEG_INF (-1e30f)
#define SCAN_B 196   // ceil(NN/256)
#define ECAP 64      // cached edges per wave in node_fused

__device__ __forceinline__ float lrelu(float v) { return v >= 0.f ? v : SLOPE * v; }

// ---------------- fp32 GEMM + fused attention coefficients, fp16 H store ----------------
// H16 = half(X @ W); asrc/adst[n,h] = <h[n,h,:], a_src/dst[h,:]> (computed in fp32)
// 64 rows x 128 cols per block, 256 threads, 8 rows x 4 cols each.
__global__ __launch_bounds__(256) void gemm_attn64(
    const float* __restrict__ X, const float* __restrict__ W,
    const float* __restrict__ a_src, const float* __restrict__ a_dst,
    __half* __restrict__ H16, float* __restrict__ asrc, float* __restrict__ adst)
{
    __shared__ float Xs[2][16][68];    // [buf][k][row], 64->68 pad
    __shared__ float Wsh[2][16][128];  // [buf][k][col]
    const int t = threadIdx.x;
    const int rowBase = blockIdx.x * 64;

    const int lr  = t >> 2;          // X row 0..63
    const int lk4 = (t & 3) * 4;     // X k offset 0,4,8,12
    const int wk  = t >> 5;          // W k row 0..7 (and +8)
    const int wc  = (t & 31) * 4;    // W col

    const int r0 = (t >> 5) * 8;     // rows r0..r0+7
    const int c0 = (t & 31) * 4;     // cols c0..c0+3

    const int xrow = min(rowBase + lr, NN - 1);

    // chunk 0 -> LDS buf 0
    float4 xv  = *(const float4*)&X[(size_t)xrow * 128 + lk4];
    float4 wv0 = *(const float4*)&W[(size_t)wk * 128 + wc];
    float4 wv1 = *(const float4*)&W[(size_t)(wk + 8) * 128 + wc];
    Xs[0][lk4 + 0][lr] = xv.x;
    Xs[0][lk4 + 1][lr] = xv.y;
    Xs[0][lk4 + 2][lr] = xv.z;
    Xs[0][lk4 + 3][lr] = xv.w;
    *(float4*)&Wsh[0][wk][wc]     = wv0;
    *(float4*)&Wsh[0][wk + 8][wc] = wv1;
    // prefetch chunk 1 into registers
    xv  = *(const float4*)&X[(size_t)xrow * 128 + 16 + lk4];
    wv0 = *(const float4*)&W[(size_t)(16 + wk) * 128 + wc];
    wv1 = *(const float4*)&W[(size_t)(16 + wk + 8) * 128 + wc];
    __syncthreads();

    float4 acc[8];
    #pragma unroll
    for (int j = 0; j < 8; ++j) acc[j] = make_float4(0.f, 0.f, 0.f, 0.f);

    #pragma unroll 1
    for (int kc = 0; kc < 8; ++kc) {
        const int cur = kc & 1;
        if (kc < 7) {   // write prefetched chunk kc+1 into the other buffer
            const int nxt = cur ^ 1;
            Xs[nxt][lk4 + 0][lr] = xv.x;
            Xs[nxt][lk4 + 1][lr] = xv.y;
            Xs[nxt][lk4 + 2][lr] = xv.z;
            Xs[nxt][lk4 + 3][lr] = xv.w;
            *(float4*)&Wsh[nxt][wk][wc]     = wv0;
            *(float4*)&Wsh[nxt][wk + 8][wc] = wv1;
        }
        if (kc < 6) {   // prefetch chunk kc+2 into registers
            const int kb = (kc + 2) * 16;
            xv  = *(const float4*)&X[(size_t)xrow * 128 + kb + lk4];
            wv0 = *(const float4*)&W[(size_t)(kb + wk) * 128 + wc];
            wv1 = *(const float4*)&W[(size_t)(kb + wk + 8) * 128 + wc];
        }
        #pragma unroll
        for (int kk = 0; kk < 16; ++kk) {
            const float4 w  = *(const float4*)&Wsh[cur][kk][c0];
            const float4 xa = *(const float4*)&Xs[cur][kk][r0];
            const float4 xb = *(const float4*)&Xs[cur][kk][r0 + 4];
            acc[0].x = fmaf(xa.x, w.x, acc[0].x); acc[0].y = fmaf(xa.x, w.y, acc[0].y);
            acc[0].z = fmaf(xa.x, w.z, acc[0].z); acc[0].w = fmaf(xa.x, w.w, acc[0].w);
            acc[1].x = fmaf(xa.y, w.x, acc[1].x); acc[1].y = fmaf(xa.y, w.y, acc[1].y);
            acc[1].z = fmaf(xa.y, w.z, acc[1].z); acc[1].w = fmaf(xa.y, w.w, acc[1].w);
            acc[2].x = fmaf(xa.z, w.x, acc[2].x); acc[2].y = fmaf(xa.z, w.y, acc[2].y);
            acc[2].z = fmaf(xa.z, w.z, acc[2].z); acc[2].w = fmaf(xa.z, w.w, acc[2].w);
            acc[3].x = fmaf(xa.w, w.x, acc[3].x); acc[3].y = fmaf(xa.w, w.y, acc[3].y);
            acc[3].z = fmaf(xa.w, w.z, acc[3].z); acc[3].w = fmaf(xa.w, w.w, acc[3].w);
            acc[4].x = fmaf(xb.x, w.x, acc[4].x); acc[4].y = fmaf(xb.x, w.y, acc[4].y);
            acc[4].z = fmaf(xb.x, w.z, acc[4].z); acc[4].w = fmaf(xb.x, w.w, acc[4].w);
            acc[5].x = fmaf(xb.y, w.x, acc[5].x); acc[5].y = fmaf(xb.y, w.y, acc[5].y);
            acc[5].z = fmaf(xb.y, w.z, acc[5].z); acc[5].w = fmaf(xb.y, w.w, acc[5].w);
            acc[6].x = fmaf(xb.z, w.x, acc[6].x); acc[6].y = fmaf(xb.z, w.y, acc[6].y);
            acc[6].z = fmaf(xb.z, w.z, acc[6].z); acc[6].w = fmaf(xb.z, w.w, acc[6].w);
            acc[7].x = fmaf(xb.w, w.x, acc[7].x); acc[7].y = fmaf(xb.w, w.y, acc[7].y);
            acc[7].z = fmaf(xb.w, w.z, acc[7].z); acc[7].w = fmaf(xb.w, w.w, acc[7].w);
        }
        __syncthreads();
    }

    // epilogue: fp16 H store + fused per-head attention dots (fp32).
    const float4 asv = *(const float4*)&a_src[c0];
    const float4 adv = *(const float4*)&a_dst[c0];
    const int cl = t & 31;
    const int hh = cl >> 2;          // head of this col group
    #pragma unroll
    for (int j = 0; j < 8; ++j) {
        const int r = rowBase + r0 + j;
        float s1 = acc[j].x * asv.x + acc[j].y * asv.y + acc[j].z * asv.z + acc[j].w * asv.w;
        float s2 = acc[j].x * adv.x + acc[j].y * adv.y + acc[j].z * adv.z + acc[j].w * adv.w;
        s1 += __shfl_xor(s1, 1); s1 += __shfl_xor(s1, 2);
        s2 += __shfl_xor(s2, 1); s2 += __shfl_xor(s2, 2);
        if (r < NN) {
            __half2 ha = __floats2half2_rn(acc[j].x, acc[j].y);
            __half2 hb = __floats2half2_rn(acc[j].z, acc[j].w);
            uint2 pk = make_uint2(*(unsigned*)&ha, *(unsigned*)&hb);
            *(uint2*)&H16[(size_t)r * 128 + c0] = pk;
            if ((cl & 3) == 0) {
                asrc[r * 8 + hh] = s1;
                adst[r * 8 + hh] = s2;
            }
        }
    }
}

// ---------------- CSR build ----------------
__global__ __launch_bounds__(256) void zero_counts(int* __restrict__ counts) {
    int i = blockIdx.x * 256 + threadIdx.x;
    if (i < NN) counts[i] = 0;
}

__global__ __launch_bounds__(256) void hist_dst(const int* __restrict__ dst,
                                                int* __restrict__ counts) {
    int e = blockIdx.x * 256 + threadIdx.x;
    if (e >= NE) return;
    int d = dst[e];
    if ((unsigned)d >= NN) d = 0;
    atomicAdd(&counts[d], 1);
}

__global__ __launch_bounds__(256) void block_sum(const int* __restrict__ counts,
                                                 int* __restrict__ bsum) {
    __shared__ int red[256];
    int t = threadIdx.x, i = blockIdx.x * 256 + t;
    red[t] = (i < NN) ? counts[i] : 0;
    __syncthreads();
    for (int s = 128; s > 0; s >>= 1) {
        if (t < s) red[t] += red[t + s];
        __syncthreads();
    }
    if (t == 0) bsum[blockIdx.x] = red[0];
}

__global__ __launch_bounds__(256) void scan_bsum(const int* __restrict__ bsum,
                                                 int* __restrict__ boff) {
    __shared__ int sh[256];
    int t = threadIdx.x;
    int v = (t < SCAN_B) ? bsum[t] : 0;
    sh[t] = v;
    __syncthreads();
    for (int d = 1; d < 256; d <<= 1) {
        int u = (t >= d) ? sh[t - d] : 0;
        __syncthreads();
        sh[t] += u;
        __syncthreads();
    }
    if (t < SCAN_B) boff[t] = sh[t] - v;   // exclusive
}

__global__ __launch_bounds__(256) void scan_final(
    const int* __restrict__ counts, const int* __restrict__ boff,
    int* __restrict__ off, int* __restrict__ cursor)
{
    __shared__ int sh[256];
    int t = threadIdx.x, i = blockIdx.x * 256 + t;
    int v = (i < NN) ? counts[i] : 0;
    sh[t] = v;
    __syncthreads();
    for (int d = 1; d < 256; d <<= 1) {
        int u = (t >= d) ? sh[t - d] : 0;
        __syncthreads();
        sh[t] += u;
        __syncthreads();
    }
    if (i < NN) {
        int o = boff[blockIdx.x] + sh[t] - v;
        off[i] = o;
        cursor[i] = o;
        if (i == NN - 1) off[NN] = o + v;
    }
}

__global__ __launch_bounds__(256) void scatter_csr(
    const int* __restrict__ src, const int* __restrict__ dst,
    int* __restrict__ cursor, int* __restrict__ csrE, int* __restrict__ csrS) {
    int e = blockIdx.x * 256 + threadIdx.x;
    if (e >= NE) return;
    int s = src[e], d = dst[e];
    if ((unsigned)s >= NN) s = 0;
    if ((unsigned)d >= NN) d = 0;
    int pos = atomicAdd(&cursor[d], 1);
    csrE[pos] = e;
    csrS[pos] = s;
}

// ---------------- fused per-node softmax + aggregate (one wave per node) ----------------
// Phase 2 gathers fp16 H rows: one quarter-wave (16 lanes x 8 halves) per edge row.
__global__ __launch_bounds__(256) void node_fused(
    const int* __restrict__ off, const int* __restrict__ csrE, const int* __restrict__ csrS,
    const float* __restrict__ asrc, const float* __restrict__ adst,
    const __half* __restrict__ H16, const float* __restrict__ bias,
    float* __restrict__ alpha, float* __restrict__ out)
{
    __shared__ float ecache[4][ECAP * 8];   // per-wave e-values [i][h]
    __shared__ int   scache[4][ECAP];       // per-wave src ids
    const int w = threadIdx.x >> 6;         // wave within block
    int wid = (blockIdx.x * 256 + threadIdx.x) >> 6;
    if (wid >= NN) return;
    const int lane = threadIdx.x & 63;
    const int n = wid;
    const int p0 = off[n], p1 = off[n + 1];
    const int deg = p1 - p0;
    const int h = lane & 7;      // head (softmax lanes)
    const int el = lane >> 3;    // edge-local slot 0..7
    const float ad = adst[n * 8 + h];

    // phase 1: online (max, sum), caching e-values + src ids in LDS
    float m = NEG_INF, l = 0.f;
    for (int base = 0; base < deg; base += 8) {
        int i = base + el;
        if (i < deg) {
            int s = csrS[p0 + i];
            float v = lrelu(asrc[s * 8 + h] + ad);
            if (i < ECAP) {
                ecache[w][i * 8 + h] = v;
                if (h == 0) scache[w][i] = s;
            }
            float nm = fmaxf(m, v);
            l = l * __expf(m - nm) + __expf(v - nm);
            m = nm;
        }
    }
    #pragma unroll
    for (int msk = 8; msk <= 32; msk <<= 1) {
        float m2 = __shfl_xor(m, msk);
        float l2 = __shfl_xor(l, msk);
        float nm = fmaxf(m, m2);
        l = l * __expf(m - nm) + l2 * __expf(m2 - nm);
        m = nm;
    }
    const float inv = 1.f / (l + 1e-16f);

    // phase 2: alpha write + fp16 gather-aggregate.
    // Quarter q handles edge slots k with k%4==q; channels ql*8..ql*8+7.
    // Convergent loops only: uniform trip count, clamped shfl index,
    // branchless predication (divergent __shfl is UB — round-4 lesson).
    const int q  = lane >> 4;
    const int ql = lane & 15;
    const int hq = ql >> 1;          // head of this channel group
    float4 accA = make_float4(0.f, 0.f, 0.f, 0.f);
    float4 accB = make_float4(0.f, 0.f, 0.f, 0.f);
    for (int base = 0; base < deg; base += 8) {
        int i = base + el;
        float a = 0.f;
        int s = 0;
        if (i < deg) {
            int p = p0 + i;
            int e = csrE[p];
            float v;
            if (i < ECAP) {
                s = scache[w][i];
                v = ecache[w][i * 8 + h];
            } else {
                s = csrS[p];
                v = lrelu(asrc[s * 8 + h] + ad);
            }
            a = __expf(v - m) * inv;
            alpha[(size_t)e * 8 + h] = a;
        }
        const int cnt = min(8, deg - base);
        for (int kb = 0; kb < cnt; kb += 4) {          // uniform trip count
            const int kw = kb + q;                     // this quarter's edge slot
            const int kc = min(kw, cnt - 1);           // clamped valid slot
            float ak = __shfl(a, kc * 8 + hq);
            int   sk = __shfl(s, kc * 8);
            const float am = (kw < cnt) ? ak : 0.f;    // branchless predication
            float4 raw = *(const float4*)&H16[(size_t)sk * 128 + ql * 8];
            const __half2* ph = (const __half2*)&raw;
            const float2 f0 = __half22float2(ph[0]);
            const float2 f1 = __half22float2(ph[1]);
            const float2 f2 = __half22float2(ph[2]);
            const float2 f3 = __half22float2(ph[3]);
            accA.x = fmaf(f0.x, am, accA.x);
            accA.y = fmaf(f0.y, am, accA.y);
            accA.z = fmaf(f1.x, am, accA.z);
            accA.w = fmaf(f1.y, am, accA.w);
            accB.x = fmaf(f2.x, am, accB.x);
            accB.y = fmaf(f2.y, am, accB.y);
            accB.z = fmaf(f3.x, am, accB.z);
            accB.w = fmaf(f3.y, am, accB.w);
        }
    }
    // combine quarters: lanes {ql, ql+16, ql+32, ql+48} hold same channels
    accA.x += __shfl_xor(accA.x, 16); accA.x += __shfl_xor(accA.x, 32);
    accA.y += __shfl_xor(accA.y, 16); accA.y += __shfl_xor(accA.y, 32);
    accA.z += __shfl_xor(accA.z, 16); accA.z += __shfl_xor(accA.z, 32);
    accA.w += __shfl_xor(accA.w, 16); accA.w += __shfl_xor(accA.w, 32);
    accB.x += __shfl_xor(accB.x, 16); accB.x += __shfl_xor(accB.x, 32);
    accB.y += __shfl_xor(accB.y, 16); accB.y += __shfl_xor(accB.y, 32);
    accB.z += __shfl_xor(accB.z, 16); accB.z += __shfl_xor(accB.z, 32);
    accB.w += __shfl_xor(accB.w, 16); accB.w += __shfl_xor(accB.w, 32);
    if (q == 0) {
        const float4 bva = *(const float4*)&bias[ql * 8];
        const float4 bvb = *(const float4*)&bias[ql * 8 + 4];
        float4 oa, ob;
        oa.x = accA.x + bva.x; oa.y = accA.y + bva.y;
        oa.z = accA.z + bva.z; oa.w = accA.w + bva.w;
        ob.x = accB.x + bvb.x; ob.y = accB.y + bvb.y;
        ob.z = accB.z + bvb.z; ob.w = accB.w + bvb.w;
        *(float4*)&out[(size_t)n * 128 + ql * 8]     = oa;
        *(float4*)&out[(size_t)n * 128 + ql * 8 + 4] = ob;
    }
}

extern "C" void kernel_launch(void* const* d_in, const int* in_sizes, int n_in,
                              void* d_out, int out_size, void* d_ws, size_t ws_size,
                              hipStream_t stream)
{
    const float* x   = (const float*)d_in[0];
    const float* W1  = (const float*)d_in[1];
    const float* as1 = (const float*)d_in[2];
    const float* ad1 = (const float*)d_in[3];
    const float* b1  = (const float*)d_in[4];
    const float* W2  = (const float*)d_in[5];
    const float* as2 = (const float*)d_in[6];
    const float* ad2 = (const float*)d_in[7];
    const float* b2  = (const float*)d_in[8];
    const int*   ei  = (const int*)d_in[9];
    const int* srcp = ei;
    const int* dstp = ei + NE;

    float* outx   = (float*)d_out;            // [NN*128]
    float* alpha1 = outx + (size_t)NN * 128;  // [NE*8]
    float* alpha2 = alpha1 + (size_t)NE * 8;  // [NE*8]

    __half* h16 = (__half*)d_ws;                       // NN*128 halves
    float* x1   = (float*)(h16 + (size_t)NN * 128);    // NN*128 fp32
    float* asrc = x1 + (size_t)NN * 128;               // NN*8
    float* adst = asrc + (size_t)NN * 8;               // NN*8
    int* counts = (int*)(adst + (size_t)NN * 8);       // NN
    int* off    = counts + NN;                          // NN+1
    int* cursor = off + NN + 1;                         // NN
    int* csrE   = cursor + NN;                          // NE
    int* csrS   = csrE + NE;                            // NE
    int* bsum   = csrS + NE;                            // SCAN_B
    int* boff   = bsum + SCAN_B;                        // SCAN_B

    int gemmGrid = (NN + 63) / 64;
    int nodeGrid = (NN + 3) / 4;           // 4 waves (nodes) per 256-thread block
    int edgeGrid = (NE + 255) / 256;
    int cntGrid  = (NN + 255) / 256;

    // ---- CSR build (shared by both layers) ----
    zero_counts<<<cntGrid, 256, 0, stream>>>(counts);
    hist_dst<<<edgeGrid, 256, 0, stream>>>(dstp, counts);
    block_sum<<<SCAN_B, 256, 0, stream>>>(counts, bsum);
    scan_bsum<<<1, 256, 0, stream>>>(bsum, boff);
    scan_final<<<SCAN_B, 256, 0, stream>>>(counts, boff, off, cursor);
    scatter_csr<<<edgeGrid, 256, 0, stream>>>(srcp, dstp, cursor, csrE, csrS);

    // ---- layer 1 ----
    gemm_attn64<<<gemmGrid, 256, 0, stream>>>(x, W1, as1, ad1, h16, asrc, adst);
    node_fused<<<nodeGrid, 256, 0, stream>>>(off, csrE, csrS, asrc, adst, h16, b1, alpha1, x1);

    // ---- layer 2 ----
    gemm_attn64<<<gemmGrid, 256, 0, stream>>>(x1, W2, as2, ad2, h16, asrc, adst);
    node_fused<<<nodeGrid, 256, 0, stream>>>(off, csrE, csrS, asrc, adst, h16, b2, alpha2, outx);
}

// Round 8
// 260.201 us; speedup vs baseline: 15.5556x; 1.0556x over previous
//
#include <hip/hip_runtime.h>
#include <hip/hip_fp16.h>

#define NN 50000
#define NE 800000
#define SLOPE 0.2f
#define NEG_INF (-1e30f)
#define SCAN_B 196   // ceil(NN/256)
#define ECAP 64      // cached edges per wave in node_fused

typedef _Float16 half8 __attribute__((ext_vector_type(8)));
typedef float f32x4 __attribute__((ext_vector_type(4)));

__device__ __forceinline__ float lrelu(float v) { return v >= 0.f ? v : SLOPE * v; }

// ---------------- prep: WTaug = [W^T | u_src | u_dst] in fp16 ----------------
// WTaug is [144][128] halves: row c<128 = W[:,c]; rows 128..135 = u_src[:,h];
// rows 136..143 = u_dst[:,h]. u_src[k][h] = sum_c W[k][16h+c]*a_src[h][c]
// (associativity: (X@W)@a == X@(W@a) per head-block).
__global__ __launch_bounds__(256) void prep_w(
    const float* __restrict__ W, const float* __restrict__ as_, const float* __restrict__ ad_,
    __half* __restrict__ WT)
{
    const int t0 = blockIdx.x * 256 + threadIdx.x;
    const int stride = gridDim.x * 256;
    for (int idx = t0; idx < 1024; idx += stride) {   // (k,h) pairs
        const int k = idx >> 3, h = idx & 7;
        float s1 = 0.f, s2 = 0.f;
        #pragma unroll
        for (int c = 0; c < 16; ++c) {
            const float w = W[k * 128 + h * 16 + c];
            s1 += w * as_[h * 16 + c];
            s2 += w * ad_[h * 16 + c];
        }
        WT[(size_t)(128 + h) * 128 + k] = (__half)s1;
        WT[(size_t)(136 + h) * 128 + k] = (__half)s2;
    }
    for (int idx = t0; idx < 16384; idx += stride) {  // transpose W
        const int k = idx >> 7, c = idx & 127;
        WT[(size_t)c * 128 + k] = (__half)W[idx];
    }
}

// ---------------- MFMA GEMM: H16 = f16(X @ W), asrc/adst fused as cols 128..143 ----
// 64 rows/block (4 waves x 16 rows), 9 col-tiles of 16. No LDS, no barriers.
// A-frag: lane reads 8 contiguous k from its row (k-map consistent with B-frag:
// correctness is invariant to the k-permutation as long as A/B agree).
// C/D layout (m89-verified): col=lane&15, row=4*(lane>>4)+reg.
template<bool F32IN>
__global__ __launch_bounds__(256) void mfma_gemm(
    const void* __restrict__ Xin, const __half* __restrict__ WT,
    __half* __restrict__ H16, float* __restrict__ asrc, float* __restrict__ adst)
{
    const int t = threadIdx.x;
    const int w = t >> 6;
    const int lane = t & 63;
    const int r16 = lane & 15;
    const int g = lane >> 4;
    const int rowStrip = blockIdx.x * 64 + w * 16;
    const int rowm = min(rowStrip + r16, NN - 1);

    half8 afr[4];
    if constexpr (F32IN) {
        const float* xr = (const float*)Xin + (size_t)rowm * 128;
        #pragma unroll
        for (int ks = 0; ks < 4; ++ks) {
            const int k0 = ks * 32 + 8 * g;
            const float4 p = *(const float4*)&xr[k0];
            const float4 q = *(const float4*)&xr[k0 + 4];
            half8 a;
            a[0] = (_Float16)p.x; a[1] = (_Float16)p.y; a[2] = (_Float16)p.z; a[3] = (_Float16)p.w;
            a[4] = (_Float16)q.x; a[5] = (_Float16)q.y; a[6] = (_Float16)q.z; a[7] = (_Float16)q.w;
            afr[ks] = a;
        }
    } else {
        const __half* xr = (const __half*)Xin + (size_t)rowm * 128;
        #pragma unroll
        for (int ks = 0; ks < 4; ++ks) {
            afr[ks] = *(const half8*)&xr[ks * 32 + 8 * g];
        }
    }

    for (int ct = 0; ct < 9; ++ct) {
        f32x4 acc = {0.f, 0.f, 0.f, 0.f};
        const __half* wrow = WT + (size_t)(ct * 16 + r16) * 128 + 8 * g;
        #pragma unroll
        for (int ks = 0; ks < 4; ++ks) {
            const half8 b = *(const half8*)&wrow[ks * 32];
            acc = __builtin_amdgcn_mfma_f32_16x16x32_f16(afr[ks], b, acc, 0, 0, 0);
        }
        if (ct < 8) {
            #pragma unroll
            for (int rr = 0; rr < 4; ++rr) {
                const int r = rowStrip + 4 * g + rr;
                if (r < NN) H16[(size_t)r * 128 + ct * 16 + r16] = (__half)acc[rr];
            }
        } else {
            #pragma unroll
            for (int rr = 0; rr < 4; ++rr) {
                const int r = rowStrip + 4 * g + rr;
                if (r < NN) {
                    if (r16 < 8) asrc[(size_t)r * 8 + r16] = acc[rr];
                    else         adst[(size_t)r * 8 + (r16 - 8)] = acc[rr];
                }
            }
        }
    }
}

// ---------------- CSR build ----------------
__global__ __launch_bounds__(256) void zero_counts(int* __restrict__ counts) {
    int i = blockIdx.x * 256 + threadIdx.x;
    if (i < NN) counts[i] = 0;
}

__global__ __launch_bounds__(256) void hist_dst(const int* __restrict__ dst,
                                                int* __restrict__ counts) {
    int e = blockIdx.x * 256 + threadIdx.x;
    if (e >= NE) return;
    int d = dst[e];
    if ((unsigned)d >= NN) d = 0;
    atomicAdd(&counts[d], 1);
}

__global__ __launch_bounds__(256) void block_sum(const int* __restrict__ counts,
                                                 int* __restrict__ bsum) {
    __shared__ int red[256];
    int t = threadIdx.x, i = blockIdx.x * 256 + t;
    red[t] = (i < NN) ? counts[i] : 0;
    __syncthreads();
    for (int s = 128; s > 0; s >>= 1) {
        if (t < s) red[t] += red[t + s];
        __syncthreads();
    }
    if (t == 0) bsum[blockIdx.x] = red[0];
}

__global__ __launch_bounds__(256) void scan_bsum(const int* __restrict__ bsum,
                                                 int* __restrict__ boff) {
    __shared__ int sh[256];
    int t = threadIdx.x;
    int v = (t < SCAN_B) ? bsum[t] : 0;
    sh[t] = v;
    __syncthreads();
    for (int d = 1; d < 256; d <<= 1) {
        int u = (t >= d) ? sh[t - d] : 0;
        __syncthreads();
        sh[t] += u;
        __syncthreads();
    }
    if (t < SCAN_B) boff[t] = sh[t] - v;   // exclusive
}

__global__ __launch_bounds__(256) void scan_final(
    const int* __restrict__ counts, const int* __restrict__ boff,
    int* __restrict__ off, int* __restrict__ cursor)
{
    __shared__ int sh[256];
    int t = threadIdx.x, i = blockIdx.x * 256 + t;
    int v = (i < NN) ? counts[i] : 0;
    sh[t] = v;
    __syncthreads();
    for (int d = 1; d < 256; d <<= 1) {
        int u = (t >= d) ? sh[t - d] : 0;
        __syncthreads();
        sh[t] += u;
        __syncthreads();
    }
    if (i < NN) {
        int o = boff[blockIdx.x] + sh[t] - v;
        off[i] = o;
        cursor[i] = o;
        if (i == NN - 1) off[NN] = o + v;
    }
}

__global__ __launch_bounds__(256) void scatter_csr(
    const int* __restrict__ src, const int* __restrict__ dst,
    int* __restrict__ cursor, int* __restrict__ csrE, int* __restrict__ csrS) {
    int e = blockIdx.x * 256 + threadIdx.x;
    if (e >= NE) return;
    int s = src[e], d = dst[e];
    if ((unsigned)s >= NN) s = 0;
    if ((unsigned)d >= NN) d = 0;
    int pos = atomicAdd(&cursor[d], 1);
    csrE[pos] = e;
    csrS[pos] = s;
}

// ---------------- fused per-node softmax + aggregate (one wave per node) ----------------
// Phase 2 gathers fp16 H rows: one quarter-wave (16 lanes x 8 halves) per edge row.
// OT = output type: __half for layer-1 (feeds fp16 MFMA gemm), float for final.
template<typename OT>
__global__ __launch_bounds__(256) void node_fused(
    const int* __restrict__ off, const int* __restrict__ csrE, const int* __restrict__ csrS,
    const float* __restrict__ asrc, const float* __restrict__ adst,
    const __half* __restrict__ H16, const float* __restrict__ bias,
    float* __restrict__ alpha, OT* __restrict__ out)
{
    __shared__ float ecache[4][ECAP * 8];   // per-wave e-values [i][h]
    __shared__ int   scache[4][ECAP];       // per-wave src ids
    const int w = threadIdx.x >> 6;         // wave within block
    int wid = (blockIdx.x * 256 + threadIdx.x) >> 6;
    if (wid >= NN) return;
    const int lane = threadIdx.x & 63;
    const int n = wid;
    const int p0 = off[n], p1 = off[n + 1];
    const int deg = p1 - p0;
    const int h = lane & 7;      // head (softmax lanes)
    const int el = lane >> 3;    // edge-local slot 0..7
    const float ad = adst[n * 8 + h];

    // phase 1: online (max, sum), caching e-values + src ids in LDS
    float m = NEG_INF, l = 0.f;
    for (int base = 0; base < deg; base += 8) {
        int i = base + el;
        if (i < deg) {
            int s = csrS[p0 + i];
            float v = lrelu(asrc[s * 8 + h] + ad);
            if (i < ECAP) {
                ecache[w][i * 8 + h] = v;
                if (h == 0) scache[w][i] = s;
            }
            float nm = fmaxf(m, v);
            l = l * __expf(m - nm) + __expf(v - nm);
            m = nm;
        }
    }
    #pragma unroll
    for (int msk = 8; msk <= 32; msk <<= 1) {
        float m2 = __shfl_xor(m, msk);
        float l2 = __shfl_xor(l, msk);
        float nm = fmaxf(m, m2);
        l = l * __expf(m - nm) + l2 * __expf(m2 - nm);
        m = nm;
    }
    const float inv = 1.f / (l + 1e-16f);

    // phase 2: alpha write + fp16 gather-aggregate.
    // Quarter q handles edge slots k with k%4==q; channels ql*8..ql*8+7.
    // Convergent loops only: uniform trip count, clamped shfl index,
    // branchless predication (divergent __shfl is UB — round-4 lesson).
    const int q  = lane >> 4;
    const int ql = lane & 15;
    const int hq = ql >> 1;          // head of this channel group
    float4 accA = make_float4(0.f, 0.f, 0.f, 0.f);
    float4 accB = make_float4(0.f, 0.f, 0.f, 0.f);
    for (int base = 0; base < deg; base += 8) {
        int i = base + el;
        float a = 0.f;
        int s = 0;
        if (i < deg) {
            int p = p0 + i;
            int e = csrE[p];
            float v;
            if (i < ECAP) {
                s = scache[w][i];
                v = ecache[w][i * 8 + h];
            } else {
                s = csrS[p];
                v = lrelu(asrc[s * 8 + h] + ad);
            }
            a = __expf(v - m) * inv;
            alpha[(size_t)e * 8 + h] = a;
        }
        const int cnt = min(8, deg - base);
        for (int kb = 0; kb < cnt; kb += 4) {          // uniform trip count
            const int kw = kb + q;                     // this quarter's edge slot
            const int kc = min(kw, cnt - 1);           // clamped valid slot
            float ak = __shfl(a, kc * 8 + hq);
            int   sk = __shfl(s, kc * 8);
            const float am = (kw < cnt) ? ak : 0.f;    // branchless predication
            float4 raw = *(const float4*)&H16[(size_t)sk * 128 + ql * 8];
            const __half2* ph = (const __half2*)&raw;
            const float2 f0 = __half22float2(ph[0]);
            const float2 f1 = __half22float2(ph[1]);
            const float2 f2 = __half22float2(ph[2]);
            const float2 f3 = __half22float2(ph[3]);
            accA.x = fmaf(f0.x, am, accA.x);
            accA.y = fmaf(f0.y, am, accA.y);
            accA.z = fmaf(f1.x, am, accA.z);
            accA.w = fmaf(f1.y, am, accA.w);
            accB.x = fmaf(f2.x, am, accB.x);
            accB.y = fmaf(f2.y, am, accB.y);
            accB.z = fmaf(f3.x, am, accB.z);
            accB.w = fmaf(f3.y, am, accB.w);
        }
    }
    // combine quarters: lanes {ql, ql+16, ql+32, ql+48} hold same channels
    accA.x += __shfl_xor(accA.x, 16); accA.x += __shfl_xor(accA.x, 32);
    accA.y += __shfl_xor(accA.y, 16); accA.y += __shfl_xor(accA.y, 32);
    accA.z += __shfl_xor(accA.z, 16); accA.z += __shfl_xor(accA.z, 32);
    accA.w += __shfl_xor(accA.w, 16); accA.w += __shfl_xor(accA.w, 32);
    accB.x += __shfl_xor(accB.x, 16); accB.x += __shfl_xor(accB.x, 32);
    accB.y += __shfl_xor(accB.y, 16); accB.y += __shfl_xor(accB.y, 32);
    accB.z += __shfl_xor(accB.z, 16); accB.z += __shfl_xor(accB.z, 32);
    accB.w += __shfl_xor(accB.w, 16); accB.w += __shfl_xor(accB.w, 32);
    if (q == 0) {
        const float4 bva = *(const float4*)&bias[ql * 8];
        const float4 bvb = *(const float4*)&bias[ql * 8 + 4];
        const float o0 = accA.x + bva.x, o1 = accA.y + bva.y;
        const float o2 = accA.z + bva.z, o3 = accA.w + bva.w;
        const float o4 = accB.x + bvb.x, o5 = accB.y + bvb.y;
        const float o6 = accB.z + bvb.z, o7 = accB.w + bvb.w;
        if constexpr (sizeof(OT) == 4) {
            float4 oa = {o0, o1, o2, o3}, ob = {o4, o5, o6, o7};
            *(float4*)&out[(size_t)n * 128 + ql * 8]     = oa;
            *(float4*)&out[(size_t)n * 128 + ql * 8 + 4] = ob;
        } else {
            __half2 p0 = __floats2half2_rn(o0, o1);
            __half2 p1 = __floats2half2_rn(o2, o3);
            __half2 p2 = __floats2half2_rn(o4, o5);
            __half2 p3 = __floats2half2_rn(o6, o7);
            uint4 pk;
            pk.x = *(unsigned*)&p0; pk.y = *(unsigned*)&p1;
            pk.z = *(unsigned*)&p2; pk.w = *(unsigned*)&p3;
            *(uint4*)&out[(size_t)n * 128 + ql * 8] = pk;
        }
    }
}

extern "C" void kernel_launch(void* const* d_in, const int* in_sizes, int n_in,
                              void* d_out, int out_size, void* d_ws, size_t ws_size,
                              hipStream_t stream)
{
    const float* x   = (const float*)d_in[0];
    const float* W1  = (const float*)d_in[1];
    const float* as1 = (const float*)d_in[2];
    const float* ad1 = (const float*)d_in[3];
    const float* b1  = (const float*)d_in[4];
    const float* W2  = (const float*)d_in[5];
    const float* as2 = (const float*)d_in[6];
    const float* ad2 = (const float*)d_in[7];
    const float* b2  = (const float*)d_in[8];
    const int*   ei  = (const int*)d_in[9];
    const int* srcp = ei;
    const int* dstp = ei + NE;

    float* outx   = (float*)d_out;            // [NN*128]
    float* alpha1 = outx + (size_t)NN * 128;  // [NE*8]
    float* alpha2 = alpha1 + (size_t)NE * 8;  // [NE*8]

    __half* h16 = (__half*)d_ws;                        // NN*128 halves
    __half* x1h = h16 + (size_t)NN * 128;               // NN*128 halves
    __half* wt1 = x1h + (size_t)NN * 128;               // 144*128 halves
    __half* wt2 = wt1 + (size_t)144 * 128;              // 144*128 halves
    float* asrc = (float*)(wt2 + (size_t)144 * 128);    // NN*8
    float* adst = asrc + (size_t)NN * 8;                // NN*8
    int* counts = (int*)(adst + (size_t)NN * 8);        // NN
    int* off    = counts + NN;                           // NN+1
    int* cursor = off + NN + 1;                          // NN
    int* csrE   = cursor + NN;                           // NE
    int* csrS   = csrE + NE;                             // NE
    int* bsum   = csrS + NE;                             // SCAN_B
    int* boff   = bsum + SCAN_B;                         // SCAN_B

    int gemmGrid = (NN + 63) / 64;
    int nodeGrid = (NN + 3) / 4;           // 4 waves (nodes) per 256-thread block
    int edgeGrid = (NE + 255) / 256;
    int cntGrid  = (NN + 255) / 256;

    // ---- weight prep + CSR build (shared by both layers) ----
    prep_w<<<8, 256, 0, stream>>>(W1, as1, ad1, wt1);
    prep_w<<<8, 256, 0, stream>>>(W2, as2, ad2, wt2);
    zero_counts<<<cntGrid, 256, 0, stream>>>(counts);
    hist_dst<<<edgeGrid, 256, 0, stream>>>(dstp, counts);
    block_sum<<<SCAN_B, 256, 0, stream>>>(counts, bsum);
    scan_bsum<<<1, 256, 0, stream>>>(bsum, boff);
    scan_final<<<SCAN_B, 256, 0, stream>>>(counts, boff, off, cursor);
    scatter_csr<<<edgeGrid, 256, 0, stream>>>(srcp, dstp, cursor, csrE, csrS);

    // ---- layer 1 ----
    mfma_gemm<true><<<gemmGrid, 256, 0, stream>>>(x, wt1, h16, asrc, adst);
    node_fused<__half><<<nodeGrid, 256, 0, stream>>>(off, csrE, csrS, asrc, adst, h16, b1, alpha1, x1h);

    // ---- layer 2 ----
    mfma_gemm<false><<<gemmGrid, 256, 0, stream>>>(x1h, wt2, h16, asrc, adst);
    node_fused<float><<<nodeGrid, 256, 0, stream>>>(off, csrE, csrS, asrc, adst, h16, b2, alpha2, outx);
}